// Round 5
// baseline (459.510 us; speedup 1.0000x reference)
//
#include <hip/hip_runtime.h>
#include <hip/hip_bf16.h>
#include <cstddef>
#include <cstdint>

#define NEG_SLOPE 0.2f
#define LN_EPS 1e-5f

typedef __attribute__((ext_vector_type(8))) short bf16x8;
typedef __attribute__((ext_vector_type(4))) float f32x4;

__device__ __forceinline__ unsigned short f2bf(float f) {
    __hip_bfloat16 h = __float2bfloat16(f);
    return *reinterpret_cast<unsigned short*>(&h);
}
__device__ __forceinline__ float bf2f(unsigned short u) {
    return __uint_as_float(((unsigned)u) << 16);
}
__device__ __forceinline__ float lrelu_exp(float e) {
    e = (e >= 0.f) ? e : NEG_SLOPE * e;
    return expf(e);
}

// ---------------------------------------------------------------------------
// GAT projection via bf16 MFMA: h = x @ W_gat, stored bf16 (hb), plus per-head
// logits a_s/a_d (fp32, reduced from the fp32 accumulator before rounding).
// ---------------------------------------------------------------------------
__global__ __launch_bounds__(256, 3) void k_gat_projm(
    const float* __restrict__ x, const unsigned short* __restrict__ Wgt,
    const float* __restrict__ atts, const float* __restrict__ attd,
    unsigned short* __restrict__ hb, float* __restrict__ a_s,
    float* __restrict__ a_d, int nn)
{
    __shared__ __align__(16) unsigned short sx[64][136];   // 17.4 KB
    __shared__ __align__(16) unsigned short sw[128][136];  // 34.8 KB

    const int tid  = threadIdx.x;
    const int base = blockIdx.x * 64;
    const int lane = tid & 63;
    const int w    = tid >> 6;
    const int ln   = lane & 15;
    const int quad = lane >> 4;

    for (int i = tid; i < 2048; i += 256) {
        int row = i >> 4, c = i & 15;
        *(bf16x8*)&sw[row][c * 8] = *(const bf16x8*)(Wgt + row * 128 + c * 8);
    }
    for (int i = tid; i < 2048; i += 256) {
        int row = i >> 5, c = i & 31;
        float4 v = make_float4(0.f, 0.f, 0.f, 0.f);
        if (base + row < nn) v = ((const float4*)(x + (size_t)(base + row) * 128))[c];
        ushort4 o;
        o.x = f2bf(v.x); o.y = f2bf(v.y); o.z = f2bf(v.z); o.w = f2bf(v.w);
        *(ushort4*)&sx[row][c * 4] = o;
    }
    __syncthreads();

    bf16x8 a[4];
    #pragma unroll
    for (int ks = 0; ks < 4; ++ks)
        a[ks] = *(const bf16x8*)&sx[w * 16 + ln][ks * 32 + quad * 8];

    f32x4 acc[8];
    #pragma unroll
    for (int nt = 0; nt < 8; ++nt) acc[nt] = (f32x4){0.f, 0.f, 0.f, 0.f};

    #pragma unroll
    for (int nt = 0; nt < 8; ++nt)
        #pragma unroll
        for (int ks = 0; ks < 4; ++ks) {
            bf16x8 b = *(const bf16x8*)&sw[nt * 16 + ln][ks * 32 + quad * 8];
            acc[nt] = __builtin_amdgcn_mfma_f32_16x16x32_bf16(a[ks], b, acc[nt], 0, 0, 0);
        }

    #pragma unroll
    for (int nt = 0; nt < 8; ++nt) {
        float av = atts[nt * 16 + ln];
        float dv = attd[nt * 16 + ln];
        #pragma unroll
        for (int r = 0; r < 4; ++r) {
            int node = base + w * 16 + quad * 4 + r;
            float val = acc[nt][r];
            float ps = val * av, pd = val * dv;
            #pragma unroll
            for (int off = 1; off < 16; off <<= 1) {
                ps += __shfl_xor(ps, off, 16);
                pd += __shfl_xor(pd, off, 16);
            }
            if (node < nn) {
                hb[(size_t)node * 128 + nt * 16 + ln] = f2bf(val);
                if (ln == 0) {
                    a_s[(size_t)node * 8 + nt] = ps;
                    a_d[(size_t)node * 8 + nt] = pd;
                }
            }
        }
    }
}

// ---------------------------------------------------------------------------
// CSR binning: deg histogram -> two-level exclusive scan -> scatter.
// ---------------------------------------------------------------------------
__global__ __launch_bounds__(256) void k_deg(
    const int* __restrict__ ei, int* __restrict__ deg, int E)
{
    int e = blockIdx.x * 256 + threadIdx.x;
    if (e < E) atomicAdd(&deg[ei[(size_t)E + e]], 1);
}

__global__ __launch_bounds__(256) void k_scan_blk(
    const int* __restrict__ deg, int* __restrict__ bsum, int nn)
{
    __shared__ int ws[4];
    const int tid = threadIdx.x;
    const int base = blockIdx.x * 1024 + tid * 4;
    int4 v = make_int4(0, 0, 0, 0);
    if (base + 3 < nn) v = *(const int4*)(deg + base);
    else {
        if (base + 0 < nn) v.x = deg[base + 0];
        if (base + 1 < nn) v.y = deg[base + 1];
        if (base + 2 < nn) v.z = deg[base + 2];
    }
    int total = v.x + v.y + v.z + v.w;
    #pragma unroll
    for (int off = 32; off; off >>= 1) total += __shfl_xor(total, off, 64);
    if ((tid & 63) == 0) ws[tid >> 6] = total;
    __syncthreads();
    if (tid == 0) bsum[blockIdx.x] = ws[0] + ws[1] + ws[2] + ws[3];
}

__global__ __launch_bounds__(1024) void k_scan_top(int* __restrict__ bsum, int nblk)
{
    __shared__ int part[1024];
    const int tid = threadIdx.x;
    int v = (tid < nblk) ? bsum[tid] : 0;
    part[tid] = v;
    __syncthreads();
    for (int d = 1; d < 1024; d <<= 1) {
        int add = (tid >= d) ? part[tid - d] : 0;
        __syncthreads();
        part[tid] += add;
        __syncthreads();
    }
    if (tid < nblk) bsum[tid] = part[tid] - v;  // exclusive
}

__global__ __launch_bounds__(256) void k_scan_out(
    const int* __restrict__ deg, const int* __restrict__ bsum,
    int* __restrict__ ptr, int nn)
{
    __shared__ int ws[4];
    const int tid = threadIdx.x;
    const int lane = tid & 63;
    const int wid = tid >> 6;
    const int base = blockIdx.x * 1024 + tid * 4;
    int4 v = make_int4(0, 0, 0, 0);
    if (base + 3 < nn) v = *(const int4*)(deg + base);
    else {
        if (base + 0 < nn) v.x = deg[base + 0];
        if (base + 1 < nn) v.y = deg[base + 1];
        if (base + 2 < nn) v.z = deg[base + 2];
    }
    int t1 = v.x + v.y, t2 = t1 + v.z;
    int total = t2 + v.w;
    int inc = total;
    #pragma unroll
    for (int off = 1; off < 64; off <<= 1) {
        int y = __shfl_up(inc, off, 64);
        if (lane >= off) inc += y;
    }
    int wexcl = inc - total;
    if (lane == 63) ws[wid] = inc;
    __syncthreads();
    int woff = 0;
    #pragma unroll
    for (int i = 0; i < 4; ++i) if (i < wid) woff += ws[i];
    int e0 = bsum[blockIdx.x] + woff + wexcl;
    int4 o;
    o.x = e0; o.y = e0 + v.x; o.z = e0 + t1; o.w = e0 + t2;
    if (base + 3 < nn) *(int4*)(ptr + base) = o;
    else {
        if (base + 0 < nn) ptr[base + 0] = o.x;
        if (base + 1 < nn) ptr[base + 1] = o.y;
        if (base + 2 < nn) ptr[base + 2] = o.z;
    }
}

__global__ __launch_bounds__(256) void k_scatter(
    const int* __restrict__ ei, int* __restrict__ ptr,
    int* __restrict__ esrc, int E)
{
    int e = blockIdx.x * 256 + threadIdx.x;
    if (e < E) {
        int pos = atomicAdd(&ptr[ei[(size_t)E + e]], 1);
        esrc[pos] = ei[e];
    }
}

// ---------------------------------------------------------------------------
// Gather + softmax + self-loop + residual + LN1 fused. Half-wave per dst.
// ---------------------------------------------------------------------------
__global__ __launch_bounds__(256) void k_gather(
    const int* __restrict__ esrc, const int* __restrict__ ptr,
    const unsigned short* __restrict__ hb, const float* __restrict__ a_s,
    const float* __restrict__ a_d, const float* __restrict__ x,
    const float* __restrict__ bgat, const float* __restrict__ g1,
    const float* __restrict__ b1, unsigned short* __restrict__ h1b, int nn)
{
    int d = (blockIdx.x * 256 + threadIdx.x) >> 5;
    if (d >= nn) return;
    const int l = threadIdx.x & 31;
    const int head = l >> 2;

    const int start = (d == 0) ? 0 : ptr[d - 1];
    const int end = ptr[d];
    const float ad = a_d[(size_t)d * 8 + head];

    float4 acc = make_float4(0.f, 0.f, 0.f, 0.f);
    float wsum = 0.f;
    int e = start;
    for (; e + 4 <= end; e += 4) {
        int s0 = esrc[e + 0], s1 = esrc[e + 1], s2 = esrc[e + 2], s3 = esrc[e + 3];
        float as0 = a_s[(size_t)s0 * 8 + head];
        float as1 = a_s[(size_t)s1 * 8 + head];
        float as2 = a_s[(size_t)s2 * 8 + head];
        float as3 = a_s[(size_t)s3 * 8 + head];
        ushort4 h0 = *(const ushort4*)(hb + (size_t)s0 * 128 + 4 * l);
        ushort4 h1 = *(const ushort4*)(hb + (size_t)s1 * 128 + 4 * l);
        ushort4 h2 = *(const ushort4*)(hb + (size_t)s2 * 128 + 4 * l);
        ushort4 h3 = *(const ushort4*)(hb + (size_t)s3 * 128 + 4 * l);
        float w0 = lrelu_exp(as0 + ad);
        float w1 = lrelu_exp(as1 + ad);
        float w2 = lrelu_exp(as2 + ad);
        float w3 = lrelu_exp(as3 + ad);
        acc.x += w0 * bf2f(h0.x) + w1 * bf2f(h1.x) + w2 * bf2f(h2.x) + w3 * bf2f(h3.x);
        acc.y += w0 * bf2f(h0.y) + w1 * bf2f(h1.y) + w2 * bf2f(h2.y) + w3 * bf2f(h3.y);
        acc.z += w0 * bf2f(h0.z) + w1 * bf2f(h1.z) + w2 * bf2f(h2.z) + w3 * bf2f(h3.z);
        acc.w += w0 * bf2f(h0.w) + w1 * bf2f(h1.w) + w2 * bf2f(h2.w) + w3 * bf2f(h3.w);
        wsum += (w0 + w1) + (w2 + w3);
    }
    for (; e < end; ++e) {
        int s = esrc[e];
        float w = lrelu_exp(a_s[(size_t)s * 8 + head] + ad);
        ushort4 hv = *(const ushort4*)(hb + (size_t)s * 128 + 4 * l);
        acc.x += w * bf2f(hv.x); acc.y += w * bf2f(hv.y);
        acc.z += w * bf2f(hv.z); acc.w += w * bf2f(hv.w);
        wsum += w;
    }
    {   // self loop
        float w = lrelu_exp(a_s[(size_t)d * 8 + head] + ad);
        ushort4 hv = *(const ushort4*)(hb + (size_t)d * 128 + 4 * l);
        acc.x += w * bf2f(hv.x); acc.y += w * bf2f(hv.y);
        acc.z += w * bf2f(hv.z); acc.w += w * bf2f(hv.w);
        wsum += w;
    }
    const float inv_dn = 1.f / wsum;
    float4 xv = *(const float4*)(x + (size_t)d * 128 + 4 * l);
    float4 bg = *(const float4*)(bgat + 4 * l);
    float v0 = xv.x + acc.x * inv_dn + bg.x;
    float v1 = xv.y + acc.y * inv_dn + bg.y;
    float v2 = xv.z + acc.z * inv_dn + bg.z;
    float v3 = xv.w + acc.w * inv_dn + bg.w;

    float s = v0 + v1 + v2 + v3;
    #pragma unroll
    for (int off = 16; off; off >>= 1) s += __shfl_xor(s, off, 32);
    float mu = s * (1.f / 128.f);
    float d0 = v0 - mu, d1 = v1 - mu, d2 = v2 - mu, d3 = v3 - mu;
    float q = d0 * d0 + d1 * d1 + d2 * d2 + d3 * d3;
    #pragma unroll
    for (int off = 16; off; off >>= 1) q += __shfl_xor(q, off, 32);
    float inv = rsqrtf(q * (1.f / 128.f) + LN_EPS);

    float4 gv = ((const float4*)g1)[l];
    float4 bv = ((const float4*)b1)[l];
    ushort4 ob;
    ob.x = f2bf(d0 * inv * gv.x + bv.x);
    ob.y = f2bf(d1 * inv * gv.y + bv.y);
    ob.z = f2bf(d2 * inv * gv.z + bv.z);
    ob.w = f2bf(d3 * inv * gv.w + bv.w);
    ((ushort4*)(h1b + (size_t)d * 128))[l] = ob;
}

// ---------------------------------------------------------------------------
// Weight convert for k_ffu's direct-from-global fragment loads (no LDS).
//   W1c: [512 ffrow][128 k]     W1c[n][k] = W1[k][n]   (plain transpose)
//   W2p: [8 c][128 outrow][64], element (c,row,8g+j) holds W2[ff][row],
//        g = ks2*4+q, ff = c*64 + 32*ks2 + perm(q,j),
//        perm(q,j) = j<4 ? 4q+j : 16+4q+(j-4)  (ff2 A-frag register k-order)
// (No XOR bank swizzle anymore -- no LDS in k_ffu.)
// ---------------------------------------------------------------------------
__global__ __launch_bounds__(256) void k_cvt(
    const float* __restrict__ W1, const float* __restrict__ W2,
    const float* __restrict__ Wg,
    unsigned short* __restrict__ W1c, unsigned short* __restrict__ W2p,
    unsigned short* __restrict__ Wgt)
{
    int t = blockIdx.x * 256 + threadIdx.x;
    if (t < 512 * 128) {
        // W1c: plain transpose
        int n = t >> 7, k = t & 127;
        W1c[t] = f2bf(W1[(size_t)k * 512 + n]);
        // W2p: k-permuted only
        int j2 = t & 7, g2 = (t >> 3) & 7, row = (t >> 6) & 127, c = t >> 13;
        int q = g2 & 3, ks2 = g2 >> 2;
        int ff = c * 64 + 32 * ks2 + (j2 < 4 ? 4 * q + j2 : 16 + 4 * q + (j2 - 4));
        W2p[t] = f2bf(W2[(size_t)ff * 128 + row]);
        if (t < 128 * 128) {
            int n3 = t >> 7, k3 = t & 127;
            Wgt[t] = f2bf(Wg[(size_t)k3 * 128 + n3]);
        }
    }
}

// ---------------------------------------------------------------------------
// Fully fused FF: out = LN2( relu(h1 @ W1 + b1) @ W2 + b2 + h1 ).
// NO LDS, NO BARRIERS: weight fragments are wave-uniform and identical across
// all waves (node dim lives in registers), so LDS staging was pure broadcast
// paid for with a vmcnt(0)+barrier drain every chunk (the R1-R4 ceiling).
// Instead each wave loads W1/W2 fragments straight from global: per-step
// working set is 16 KB -> L1-resident; all waves read the same 256 KB stream
// -> L2 hits. Compiler free-schedules 16 independent loads ahead of 32 MFMAs;
// occupancy is VGPR-limited only, waves fully independent.
// Geometry: 256 thr = 4 waves x 32 nodes = 128 nodes/block, grid 782.
// ---------------------------------------------------------------------------
__global__ __launch_bounds__(256, 2) void k_ffu(
    const unsigned short* __restrict__ h1b,
    const unsigned short* __restrict__ W1c,   // [512][128]
    const unsigned short* __restrict__ W2p,   // [8][128][64] k-permuted
    const float* __restrict__ b1, const float* __restrict__ b2,
    const float* __restrict__ g2, const float* __restrict__ bln2,
    float* __restrict__ out, int nn)
{
    const int tid  = threadIdx.x;        // 0..255
    const int base = blockIdx.x * 128;
    const int lane = tid & 63;
    const int w    = tid >> 6;           // 0..3
    const int ln   = lane & 15;
    const int quad = lane >> 4;

    // persistent h1 fragments (B-operand of swapped ff1)
    const bf16x8 zf = {0, 0, 0, 0, 0, 0, 0, 0};
    bf16x8 hfrag[2][4];
    #pragma unroll
    for (int mt = 0; mt < 2; ++mt) {
        int node = base + w * 32 + mt * 16 + ln;
        #pragma unroll
        for (int ks = 0; ks < 4; ++ks)
            hfrag[mt][ks] = (node < nn)
                ? *(const bf16x8*)(h1b + (size_t)node * 128 + ks * 32 + quad * 8)
                : zf;
    }

    f32x4 acc2[2][8];
    #pragma unroll
    for (int mt = 0; mt < 2; ++mt)
        #pragma unroll
        for (int nt = 0; nt < 8; ++nt)
            acc2[mt][nt] = (f32x4){0.f, 0.f, 0.f, 0.f};

    // lane-fixed base pointers
    const unsigned short* w1p = W1c + (size_t)ln * 128 + quad * 8;
    const unsigned short* w2b = W2p + (size_t)ln * 64 + quad * 8;

    for (int c = 0; c < 8; ++c) {
        #pragma unroll
        for (int ks2 = 0; ks2 < 2; ++ks2) {
            // ---- issue all 16 weight-fragment loads up front
            bf16x8 wa[2][4];
            #pragma unroll
            for (int fh = 0; fh < 2; ++fh)
                #pragma unroll
                for (int ks = 0; ks < 4; ++ks)
                    wa[fh][ks] = *(const bf16x8*)
                        (w1p + (size_t)(c * 64 + ks2 * 32 + fh * 16) * 128 + ks * 32);
            bf16x8 wb[8];
            #pragma unroll
            for (int nt = 0; nt < 8; ++nt)
                wb[nt] = *(const bf16x8*)
                    (w2b + (size_t)c * 8192 + (size_t)(nt * 16) * 64 + ks2 * 32);

            // ---- ff1 (swapped): t^T for ff block [c*64 + ks2*32, +32)
            f32x4 a1[2][2];
            a1[0][0] = (f32x4){0.f, 0.f, 0.f, 0.f};
            a1[0][1] = (f32x4){0.f, 0.f, 0.f, 0.f};
            a1[1][0] = (f32x4){0.f, 0.f, 0.f, 0.f};
            a1[1][1] = (f32x4){0.f, 0.f, 0.f, 0.f};
            #pragma unroll
            for (int fh = 0; fh < 2; ++fh)
                #pragma unroll
                for (int ks = 0; ks < 4; ++ks) {
                    a1[0][fh] = __builtin_amdgcn_mfma_f32_16x16x32_bf16(wa[fh][ks], hfrag[0][ks], a1[0][fh], 0, 0, 0);
                    a1[1][fh] = __builtin_amdgcn_mfma_f32_16x16x32_bf16(wa[fh][ks], hfrag[1][ks], a1[1][fh], 0, 0, 0);
                }

            // ---- bias + relu + pack to ff2 A-frag (permuted k-order, in-lane)
            float4 bLo = *(const float4*)(b1 + c * 64 + ks2 * 32 + quad * 4);
            float4 bHi = *(const float4*)(b1 + c * 64 + ks2 * 32 + 16 + quad * 4);
            bf16x8 pt[2];
            #pragma unroll
            for (int mt = 0; mt < 2; ++mt) {
                union { bf16x8 v; unsigned short u[8]; } P;
                P.u[0] = f2bf(fmaxf(a1[mt][0][0] + bLo.x, 0.f));
                P.u[1] = f2bf(fmaxf(a1[mt][0][1] + bLo.y, 0.f));
                P.u[2] = f2bf(fmaxf(a1[mt][0][2] + bLo.z, 0.f));
                P.u[3] = f2bf(fmaxf(a1[mt][0][3] + bLo.w, 0.f));
                P.u[4] = f2bf(fmaxf(a1[mt][1][0] + bHi.x, 0.f));
                P.u[5] = f2bf(fmaxf(a1[mt][1][1] + bHi.y, 0.f));
                P.u[6] = f2bf(fmaxf(a1[mt][1][2] + bHi.z, 0.f));
                P.u[7] = f2bf(fmaxf(a1[mt][1][3] + bHi.w, 0.f));
                pt[mt] = P.v;
            }

            // ---- ff2: acc2 += t_chunk @ W2_chunk
            #pragma unroll
            for (int nt = 0; nt < 8; ++nt) {
                acc2[0][nt] = __builtin_amdgcn_mfma_f32_16x16x32_bf16(pt[0], wb[nt], acc2[0][nt], 0, 0, 0);
                acc2[1][nt] = __builtin_amdgcn_mfma_f32_16x16x32_bf16(pt[1], wb[nt], acc2[1][nt], 0, 0, 0);
            }
        }
    }

    // ---- epilogue: + b2 + residual(h1) -> LN2 -> out
    float gv[8], bv[8], bb[8];
    #pragma unroll
    for (int nt = 0; nt < 8; ++nt) {
        int col = nt * 16 + ln;
        gv[nt] = g2[col]; bv[nt] = bln2[col]; bb[nt] = b2[col];
    }
    #pragma unroll
    for (int mt = 0; mt < 2; ++mt) {
        #pragma unroll
        for (int r = 0; r < 4; ++r) {
            int node = base + w * 32 + mt * 16 + quad * 4 + r;
            bool ok = node < nn;
            float v[8];
            #pragma unroll
            for (int nt = 0; nt < 8; ++nt) {
                int col = nt * 16 + ln;
                float res = ok ? bf2f(h1b[(size_t)node * 128 + col]) : 0.f;
                v[nt] = acc2[mt][nt][r] + bb[nt] + res;
            }
            float s = 0.f;
            #pragma unroll
            for (int nt = 0; nt < 8; ++nt) s += v[nt];
            #pragma unroll
            for (int off = 1; off < 16; off <<= 1) s += __shfl_xor(s, off, 16);
            float mu = s * (1.f / 128.f);
            float q = 0.f;
            #pragma unroll
            for (int nt = 0; nt < 8; ++nt) { float dd = v[nt] - mu; q += dd * dd; }
            #pragma unroll
            for (int off = 1; off < 16; off <<= 1) q += __shfl_xor(q, off, 16);
            float inv = rsqrtf(q * (1.f / 128.f) + LN_EPS);
            if (ok)
                #pragma unroll
                for (int nt = 0; nt < 8; ++nt) {
                    int col = nt * 16 + ln;
                    out[(size_t)node * 128 + col] = (v[nt] - mu) * inv * gv[nt] + bv[nt];
                }
        }
    }
}

// ---------------------------------------------------------------------------
extern "C" void kernel_launch(void* const* d_in, const int* in_sizes, int n_in,
                              void* d_out, int out_size, void* d_ws, size_t ws_size,
                              hipStream_t stream) {
    const float* x    = (const float*)d_in[0];
    const int*   ei   = (const int*)d_in[1];
    const float* Wg   = (const float*)d_in[2];
    const float* atts = (const float*)d_in[3];
    const float* attd = (const float*)d_in[4];
    const float* bgat = (const float*)d_in[5];
    const float* W1   = (const float*)d_in[6];
    const float* b1   = (const float*)d_in[7];
    const float* W2   = (const float*)d_in[8];
    const float* b2   = (const float*)d_in[9];
    const float* g1   = (const float*)d_in[10];
    const float* bln1 = (const float*)d_in[11];
    const float* g2   = (const float*)d_in[12];
    const float* bln2 = (const float*)d_in[13];
    float* out = (float*)d_out;

    const int nn = in_sizes[0] / 128;
    const int E  = in_sizes[1] / 2;
    const int nblk = (nn + 1023) / 1024;

    // workspace: W1c | W2p | Wgt | h1b | hb | a_s | a_d | deg | ptr | bsum | esrc
    uintptr_t pa = ((uintptr_t)d_ws + 15) & ~(uintptr_t)15;
    unsigned short* W1c = (unsigned short*)pa;
    unsigned short* W2p = W1c + 512 * 128;
    unsigned short* Wgt = W2p + 128 * 512;
    unsigned short* h1b = Wgt + 128 * 128;
    unsigned short* hb  = h1b + (size_t)nn * 128;
    float* a_s = (float*)(hb + (size_t)nn * 128);
    float* a_d = a_s + (size_t)nn * 8;
    int*   deg = (int*)(a_d + (size_t)nn * 8);
    int*   ptr = deg + nn;
    int*   bsum = ptr + nn;
    int*   esrc = bsum + 1024;

    hipMemsetAsync(deg, 0, (size_t)nn * sizeof(int), stream);

    k_cvt<<<dim3(256), dim3(256), 0, stream>>>(W1, W2, Wg, W1c, W2p, Wgt);
    k_gat_projm<<<dim3((nn + 63) / 64), dim3(256), 0, stream>>>(
        x, Wgt, atts, attd, hb, a_s, a_d, nn);
    k_deg<<<dim3((E + 255) / 256), dim3(256), 0, stream>>>(ei, deg, E);
    k_scan_blk<<<dim3(nblk), dim3(256), 0, stream>>>(deg, bsum, nn);
    k_scan_top<<<dim3(1), dim3(1024), 0, stream>>>(bsum, nblk);
    k_scan_out<<<dim3(nblk), dim3(256), 0, stream>>>(deg, bsum, ptr, nn);
    k_scatter<<<dim3((E + 255) / 256), dim3(256), 0, stream>>>(ei, ptr, esrc, E);
    k_gather<<<dim3((nn * 32 + 255) / 256), dim3(256), 0, stream>>>(
        esrc, ptr, hb, a_s, a_d, x, bgat, g1, bln1, h1b, nn);

    k_ffu<<<dim3((nn + 127) / 128), dim3(256), 0, stream>>>(
        h1b, W1c, W2p, b1, b2, g2, bln2, out, nn);
}

// Round 6
// 355.501 us; speedup vs baseline: 1.2926x; 1.2926x over previous
//
#include <hip/hip_runtime.h>
#include <hip/hip_bf16.h>
#include <cstddef>
#include <cstdint>

#define NEG_SLOPE 0.2f
#define LN_EPS 1e-5f

typedef __attribute__((ext_vector_type(8))) short bf16x8;
typedef __attribute__((ext_vector_type(8))) unsigned short u16x8;
typedef __attribute__((ext_vector_type(4))) float f32x4;

__device__ __forceinline__ unsigned short f2bf(float f) {
    __hip_bfloat16 h = __float2bfloat16(f);
    return *reinterpret_cast<unsigned short*>(&h);
}
__device__ __forceinline__ float bf2f(unsigned short u) {
    return __uint_as_float(((unsigned)u) << 16);
}
__device__ __forceinline__ float lrelu_exp(float e) {
    e = (e >= 0.f) ? e : NEG_SLOPE * e;
    return expf(e);
}
// async global->LDS, 16B per lane; LDS dest is wave-uniform base + lane*16
__device__ __forceinline__ void gl16(const void* g, void* l) {
    __builtin_amdgcn_global_load_lds(
        (const __attribute__((address_space(1))) unsigned int*)g,
        (__attribute__((address_space(3))) unsigned int*)l, 16, 0, 0);
}

// ---------------------------------------------------------------------------
// GAT projection via bf16 MFMA: h = x @ W_gat, stored bf16 (hb), plus per-head
// logits a_s/a_d (fp32, reduced from the fp32 accumulator before rounding).
// ---------------------------------------------------------------------------
__global__ __launch_bounds__(256, 3) void k_gat_projm(
    const float* __restrict__ x, const unsigned short* __restrict__ Wgt,
    const float* __restrict__ atts, const float* __restrict__ attd,
    unsigned short* __restrict__ hb, float* __restrict__ a_s,
    float* __restrict__ a_d, int nn)
{
    __shared__ __align__(16) unsigned short sx[64][136];   // 17.4 KB
    __shared__ __align__(16) unsigned short sw[128][136];  // 34.8 KB

    const int tid  = threadIdx.x;
    const int base = blockIdx.x * 64;
    const int lane = tid & 63;
    const int w    = tid >> 6;
    const int ln   = lane & 15;
    const int quad = lane >> 4;

    for (int i = tid; i < 2048; i += 256) {
        int row = i >> 4, c = i & 15;
        *(bf16x8*)&sw[row][c * 8] = *(const bf16x8*)(Wgt + row * 128 + c * 8);
    }
    for (int i = tid; i < 2048; i += 256) {
        int row = i >> 5, c = i & 31;
        float4 v = make_float4(0.f, 0.f, 0.f, 0.f);
        if (base + row < nn) v = ((const float4*)(x + (size_t)(base + row) * 128))[c];
        ushort4 o;
        o.x = f2bf(v.x); o.y = f2bf(v.y); o.z = f2bf(v.z); o.w = f2bf(v.w);
        *(ushort4*)&sx[row][c * 4] = o;
    }
    __syncthreads();

    bf16x8 a[4];
    #pragma unroll
    for (int ks = 0; ks < 4; ++ks)
        a[ks] = *(const bf16x8*)&sx[w * 16 + ln][ks * 32 + quad * 8];

    f32x4 acc[8];
    #pragma unroll
    for (int nt = 0; nt < 8; ++nt) acc[nt] = (f32x4){0.f, 0.f, 0.f, 0.f};

    #pragma unroll
    for (int nt = 0; nt < 8; ++nt)
        #pragma unroll
        for (int ks = 0; ks < 4; ++ks) {
            bf16x8 b = *(const bf16x8*)&sw[nt * 16 + ln][ks * 32 + quad * 8];
            acc[nt] = __builtin_amdgcn_mfma_f32_16x16x32_bf16(a[ks], b, acc[nt], 0, 0, 0);
        }

    #pragma unroll
    for (int nt = 0; nt < 8; ++nt) {
        float av = atts[nt * 16 + ln];
        float dv = attd[nt * 16 + ln];
        #pragma unroll
        for (int r = 0; r < 4; ++r) {
            int node = base + w * 16 + quad * 4 + r;
            float val = acc[nt][r];
            float ps = val * av, pd = val * dv;
            #pragma unroll
            for (int off = 1; off < 16; off <<= 1) {
                ps += __shfl_xor(ps, off, 16);
                pd += __shfl_xor(pd, off, 16);
            }
            if (node < nn) {
                hb[(size_t)node * 128 + nt * 16 + ln] = f2bf(val);
                if (ln == 0) {
                    a_s[(size_t)node * 8 + nt] = ps;
                    a_d[(size_t)node * 8 + nt] = pd;
                }
            }
        }
    }
}

// ---------------------------------------------------------------------------
// CSR binning: deg histogram -> two-level exclusive scan -> scatter.
// ---------------------------------------------------------------------------
__global__ __launch_bounds__(256) void k_deg(
    const int* __restrict__ ei, int* __restrict__ deg, int E)
{
    int e = blockIdx.x * 256 + threadIdx.x;
    if (e < E) atomicAdd(&deg[ei[(size_t)E + e]], 1);
}

__global__ __launch_bounds__(256) void k_scan_blk(
    const int* __restrict__ deg, int* __restrict__ bsum, int nn)
{
    __shared__ int ws[4];
    const int tid = threadIdx.x;
    const int base = blockIdx.x * 1024 + tid * 4;
    int4 v = make_int4(0, 0, 0, 0);
    if (base + 3 < nn) v = *(const int4*)(deg + base);
    else {
        if (base + 0 < nn) v.x = deg[base + 0];
        if (base + 1 < nn) v.y = deg[base + 1];
        if (base + 2 < nn) v.z = deg[base + 2];
    }
    int total = v.x + v.y + v.z + v.w;
    #pragma unroll
    for (int off = 32; off; off >>= 1) total += __shfl_xor(total, off, 64);
    if ((tid & 63) == 0) ws[tid >> 6] = total;
    __syncthreads();
    if (tid == 0) bsum[blockIdx.x] = ws[0] + ws[1] + ws[2] + ws[3];
}

__global__ __launch_bounds__(1024) void k_scan_top(int* __restrict__ bsum, int nblk)
{
    __shared__ int part[1024];
    const int tid = threadIdx.x;
    int v = (tid < nblk) ? bsum[tid] : 0;
    part[tid] = v;
    __syncthreads();
    for (int d = 1; d < 1024; d <<= 1) {
        int add = (tid >= d) ? part[tid - d] : 0;
        __syncthreads();
        part[tid] += add;
        __syncthreads();
    }
    if (tid < nblk) bsum[tid] = part[tid] - v;  // exclusive
}

__global__ __launch_bounds__(256) void k_scan_out(
    const int* __restrict__ deg, const int* __restrict__ bsum,
    int* __restrict__ ptr, int nn)
{
    __shared__ int ws[4];
    const int tid = threadIdx.x;
    const int lane = tid & 63;
    const int wid = tid >> 6;
    const int base = blockIdx.x * 1024 + tid * 4;
    int4 v = make_int4(0, 0, 0, 0);
    if (base + 3 < nn) v = *(const int4*)(deg + base);
    else {
        if (base + 0 < nn) v.x = deg[base + 0];
        if (base + 1 < nn) v.y = deg[base + 1];
        if (base + 2 < nn) v.z = deg[base + 2];
    }
    int t1 = v.x + v.y, t2 = t1 + v.z;
    int total = t2 + v.w;
    int inc = total;
    #pragma unroll
    for (int off = 1; off < 64; off <<= 1) {
        int y = __shfl_up(inc, off, 64);
        if (lane >= off) inc += y;
    }
    int wexcl = inc - total;
    if (lane == 63) ws[wid] = inc;
    __syncthreads();
    int woff = 0;
    #pragma unroll
    for (int i = 0; i < 4; ++i) if (i < wid) woff += ws[i];
    int e0 = bsum[blockIdx.x] + woff + wexcl;
    int4 o;
    o.x = e0; o.y = e0 + v.x; o.z = e0 + t1; o.w = e0 + t2;
    if (base + 3 < nn) *(int4*)(ptr + base) = o;
    else {
        if (base + 0 < nn) ptr[base + 0] = o.x;
        if (base + 1 < nn) ptr[base + 1] = o.y;
        if (base + 2 < nn) ptr[base + 2] = o.z;
    }
}

__global__ __launch_bounds__(256) void k_scatter(
    const int* __restrict__ ei, int* __restrict__ ptr,
    int* __restrict__ esrc, int E)
{
    int e = blockIdx.x * 256 + threadIdx.x;
    if (e < E) {
        int pos = atomicAdd(&ptr[ei[(size_t)E + e]], 1);
        esrc[pos] = ei[e];
    }
}

// ---------------------------------------------------------------------------
// Gather + softmax + self-loop + residual + LN1 fused.
// 16 lanes per dst (was 32): each lane owns 8 channels (head = l>>1), loads
// 16B ushort8 rows -> half the load instructions and half the redundant expf
// per edge, and 4 independent dst streams per wave (2x MLP for the random
// hb gathers). 4-edge software-pipelined batch.
// ---------------------------------------------------------------------------
__global__ __launch_bounds__(256) void k_gather(
    const int* __restrict__ esrc, const int* __restrict__ ptr,
    const unsigned short* __restrict__ hb, const float* __restrict__ a_s,
    const float* __restrict__ a_d, const float* __restrict__ x,
    const float* __restrict__ bgat, const float* __restrict__ g1,
    const float* __restrict__ b1, unsigned short* __restrict__ h1b, int nn)
{
    int d = (blockIdx.x * 256 + threadIdx.x) >> 4;
    if (d >= nn) return;
    const int l = threadIdx.x & 15;     // lane-in-group: 8 channels each
    const int head = l >> 1;            // 2 lanes per head

    const int start = (d == 0) ? 0 : ptr[d - 1];
    const int end = ptr[d];
    const float ad = a_d[(size_t)d * 8 + head];

    float acc[8];
    #pragma unroll
    for (int j = 0; j < 8; ++j) acc[j] = 0.f;
    float wsum = 0.f;

    int e = start;
    for (; e + 4 <= end; e += 4) {
        int s0 = esrc[e + 0], s1 = esrc[e + 1], s2 = esrc[e + 2], s3 = esrc[e + 3];
        float as0 = a_s[(size_t)s0 * 8 + head];
        float as1 = a_s[(size_t)s1 * 8 + head];
        float as2 = a_s[(size_t)s2 * 8 + head];
        float as3 = a_s[(size_t)s3 * 8 + head];
        u16x8 h0 = *(const u16x8*)(hb + (size_t)s0 * 128 + 8 * l);
        u16x8 h1 = *(const u16x8*)(hb + (size_t)s1 * 128 + 8 * l);
        u16x8 h2 = *(const u16x8*)(hb + (size_t)s2 * 128 + 8 * l);
        u16x8 h3 = *(const u16x8*)(hb + (size_t)s3 * 128 + 8 * l);
        float w0 = lrelu_exp(as0 + ad);
        float w1 = lrelu_exp(as1 + ad);
        float w2 = lrelu_exp(as2 + ad);
        float w3 = lrelu_exp(as3 + ad);
        #pragma unroll
        for (int j = 0; j < 8; ++j)
            acc[j] += w0 * bf2f(h0[j]) + w1 * bf2f(h1[j])
                    + w2 * bf2f(h2[j]) + w3 * bf2f(h3[j]);
        wsum += (w0 + w1) + (w2 + w3);
    }
    for (; e < end; ++e) {
        int s = esrc[e];
        float w = lrelu_exp(a_s[(size_t)s * 8 + head] + ad);
        u16x8 hv = *(const u16x8*)(hb + (size_t)s * 128 + 8 * l);
        #pragma unroll
        for (int j = 0; j < 8; ++j) acc[j] += w * bf2f(hv[j]);
        wsum += w;
    }
    {   // self loop
        float w = lrelu_exp(a_s[(size_t)d * 8 + head] + ad);
        u16x8 hv = *(const u16x8*)(hb + (size_t)d * 128 + 8 * l);
        #pragma unroll
        for (int j = 0; j < 8; ++j) acc[j] += w * bf2f(hv[j]);
        wsum += w;
    }
    const float inv_dn = 1.f / wsum;

    float4 xa = *(const float4*)(x + (size_t)d * 128 + 8 * l);
    float4 xb = *(const float4*)(x + (size_t)d * 128 + 8 * l + 4);
    float4 ga = *(const float4*)(bgat + 8 * l);
    float4 gb = *(const float4*)(bgat + 8 * l + 4);
    float v[8];
    v[0] = xa.x + acc[0] * inv_dn + ga.x;
    v[1] = xa.y + acc[1] * inv_dn + ga.y;
    v[2] = xa.z + acc[2] * inv_dn + ga.z;
    v[3] = xa.w + acc[3] * inv_dn + ga.w;
    v[4] = xb.x + acc[4] * inv_dn + gb.x;
    v[5] = xb.y + acc[5] * inv_dn + gb.y;
    v[6] = xb.z + acc[6] * inv_dn + gb.z;
    v[7] = xb.w + acc[7] * inv_dn + gb.w;

    float s = 0.f;
    #pragma unroll
    for (int j = 0; j < 8; ++j) s += v[j];
    #pragma unroll
    for (int off = 1; off < 16; off <<= 1) s += __shfl_xor(s, off, 16);
    float mu = s * (1.f / 128.f);
    float q = 0.f;
    #pragma unroll
    for (int j = 0; j < 8; ++j) { float dd = v[j] - mu; q += dd * dd; }
    #pragma unroll
    for (int off = 1; off < 16; off <<= 1) q += __shfl_xor(q, off, 16);
    float inv = rsqrtf(q * (1.f / 128.f) + LN_EPS);

    float4 g1a = *(const float4*)(g1 + 8 * l);
    float4 g1b = *(const float4*)(g1 + 8 * l + 4);
    float4 b1a = *(const float4*)(b1 + 8 * l);
    float4 b1b = *(const float4*)(b1 + 8 * l + 4);
    union { u16x8 v8; unsigned short u[8]; } ob;
    ob.u[0] = f2bf((v[0] - mu) * inv * g1a.x + b1a.x);
    ob.u[1] = f2bf((v[1] - mu) * inv * g1a.y + b1a.y);
    ob.u[2] = f2bf((v[2] - mu) * inv * g1a.z + b1a.z);
    ob.u[3] = f2bf((v[3] - mu) * inv * g1a.w + b1a.w);
    ob.u[4] = f2bf((v[4] - mu) * inv * g1b.x + b1b.x);
    ob.u[5] = f2bf((v[5] - mu) * inv * g1b.y + b1b.y);
    ob.u[6] = f2bf((v[6] - mu) * inv * g1b.z + b1b.z);
    ob.u[7] = f2bf((v[7] - mu) * inv * g1b.w + b1b.w);
    *(u16x8*)(h1b + (size_t)d * 128 + 8 * l) = ob.v8;
}

// ---------------------------------------------------------------------------
// Weight convert for k_ffu's global_load_lds path. LDS image must be linear,
// so the bank-conflict XOR swizzle (granule ^= row&7, i.e. byte ^= (row&7)<<4)
// and ff2's k-permute are BAKED INTO THE GLOBAL LAYOUT here (rule: swizzle
// both sides or neither).
//   W1s: [512 ffrow][128 k]  W1s[n][8g+j] = W1[8*(g^(n&7)) + j][n]
//   W2s: [8 c][128 outrow][64], element (c,row,8g+j) holds
//        W2[ff][row], ff = c*64 + 32*ks2 + perm(q,j), (ks2,q) from gr=g^(row&7)
//        perm(q,j) = j<4 ? 4q+j : 16+4q+(j-4)  (matches ff2 A-frag register order)
// ---------------------------------------------------------------------------
__global__ __launch_bounds__(256) void k_cvt(
    const float* __restrict__ W1, const float* __restrict__ W2,
    const float* __restrict__ Wg,
    unsigned short* __restrict__ W1s, unsigned short* __restrict__ W2s,
    unsigned short* __restrict__ Wgt)
{
    int t = blockIdx.x * 256 + threadIdx.x;
    if (t < 512 * 128) {
        // W1s
        int n = t >> 7, col = t & 127;
        int g = col >> 3, j = col & 7;
        int sk = 8 * (g ^ (n & 7)) + j;
        W1s[t] = f2bf(W1[(size_t)sk * 512 + n]);
        // W2s
        int j2 = t & 7, g2 = (t >> 3) & 7, row = (t >> 6) & 127, c = t >> 13;
        int gr = g2 ^ (row & 7);
        int q = gr & 3, ks2 = gr >> 2;
        int ff = c * 64 + 32 * ks2 + (j2 < 4 ? 4 * q + j2 : 16 + 4 * q + (j2 - 4));
        W2s[t] = f2bf(W2[(size_t)ff * 128 + row]);
        if (t < 128 * 128) {
            int n3 = t >> 7, k3 = t & 127;
            Wgt[t] = f2bf(Wg[(size_t)k3 * 128 + n3]);
        }
    }
}

// ---------------------------------------------------------------------------
// Fully fused FF: out = LN2( relu(h1 @ W1 + b1) @ W2 + b2 + h1 ).
// EXACT R3 version (harness-verified 65.6 us): double-buffered global_load_lds
// pipeline over 8 hidden-chunks of 64. 256 thr = 4 waves x 32 nodes =
// 128 nodes/block, grid 782 -> ~3 blocks/CU available, LDS 64 KB -> 2/CU.
// R4 (512thr/256nodes, grid 391) was SLOWER (73.3): half the CUs got a single
// block and the per-chunk vmcnt(0)+barrier then stalls the whole CU.
// R5 (no LDS, direct-global weights) was far slower (171.7): VMEM latency on
// the MFMA critical path. This structure is the measured local optimum.
// ---------------------------------------------------------------------------
__global__ __launch_bounds__(256, 2) void k_ffu(
    const unsigned short* __restrict__ h1b,
    const unsigned short* __restrict__ W1s,   // [512][128] swizzled
    const unsigned short* __restrict__ W2s,   // [8][128][64] permuted+swizzled
    const float* __restrict__ b1, const float* __restrict__ b2,
    const float* __restrict__ g2, const float* __restrict__ bln2,
    float* __restrict__ out, int nn)
{
    __shared__ __align__(16) unsigned short sw1[2][64][128];  // 2 x 16 KB
    __shared__ __align__(16) unsigned short sw2[2][128][64];  // 2 x 16 KB

    const int tid  = threadIdx.x;        // 0..255
    const int base = blockIdx.x * 128;
    const int lane = tid & 63;
    const int w    = tid >> 6;           // 0..3
    const int ln   = lane & 15;
    const int quad = lane >> 4;
    const int wun  = tid & ~63;          // w*64 (wave-uniform)

    // persistent h1 fragments (B-operand of swapped ff1)
    const bf16x8 zf = {0, 0, 0, 0, 0, 0, 0, 0};
    bf16x8 hfrag[2][4];
    #pragma unroll
    for (int mt = 0; mt < 2; ++mt) {
        int node = base + w * 32 + mt * 16 + ln;
        #pragma unroll
        for (int ks = 0; ks < 4; ++ks)
            hfrag[mt][ks] = (node < nn)
                ? *(const bf16x8*)(h1b + (size_t)node * 128 + ks * 32 + quad * 8)
                : zf;
    }

    f32x4 acc2[2][8];
    #pragma unroll
    for (int mt = 0; mt < 2; ++mt)
        #pragma unroll
        for (int nt = 0; nt < 8; ++nt)
            acc2[mt][nt] = (f32x4){0.f, 0.f, 0.f, 0.f};

    // prologue: stage chunk 0 into buffer 0 (1024 granules of 16B each array)
    #pragma unroll
    for (int i = 0; i < 4; ++i) {
        gl16(W1s + (size_t)(i * 256 + tid) * 8, &sw1[0][0][0] + (size_t)(i * 256 + wun) * 8);
        gl16(W2s + (size_t)(i * 256 + tid) * 8, &sw2[0][0][0] + (size_t)(i * 256 + wun) * 8);
    }
    asm volatile("s_waitcnt vmcnt(0)" ::: "memory");
    __syncthreads();

    for (int c = 0; c < 8; ++c) {
        const int b = c & 1;
        if (c < 7) {  // issue next chunk's loads; drained at end-of-chunk barrier
            const unsigned short* gw1 = W1s + (size_t)(c + 1) * 8192;
            const unsigned short* gw2 = W2s + (size_t)(c + 1) * 8192;
            #pragma unroll
            for (int i = 0; i < 4; ++i) {
                gl16(gw1 + (size_t)(i * 256 + tid) * 8,
                     &sw1[b ^ 1][0][0] + (size_t)(i * 256 + wun) * 8);
                gl16(gw2 + (size_t)(i * 256 + tid) * 8,
                     &sw2[b ^ 1][0][0] + (size_t)(i * 256 + wun) * 8);
            }
        }

        #pragma unroll
        for (int ks2 = 0; ks2 < 2; ++ks2) {
            // ---- ff1 (swapped): t^T for ff block [c*64 + ks2*32, +32)
            f32x4 a1[2][2];
            a1[0][0] = (f32x4){0.f, 0.f, 0.f, 0.f};
            a1[0][1] = (f32x4){0.f, 0.f, 0.f, 0.f};
            a1[1][0] = (f32x4){0.f, 0.f, 0.f, 0.f};
            a1[1][1] = (f32x4){0.f, 0.f, 0.f, 0.f};
            #pragma unroll
            for (int fh = 0; fh < 2; ++fh) {
                const int row = (ks2 * 2 + fh) * 16 + ln;
                #pragma unroll
                for (int ks = 0; ks < 4; ++ks) {
                    bf16x8 a = *(const bf16x8*)
                        &sw1[b][row][(((ks * 4 + quad) ^ (row & 7)) * 8)];
                    a1[0][fh] = __builtin_amdgcn_mfma_f32_16x16x32_bf16(a, hfrag[0][ks], a1[0][fh], 0, 0, 0);
                    a1[1][fh] = __builtin_amdgcn_mfma_f32_16x16x32_bf16(a, hfrag[1][ks], a1[1][fh], 0, 0, 0);
                }
            }
            // ---- bias + relu + pack to ff2 A-frag (permuted k-order, in-lane)
            float4 bLo = *(const float4*)(b1 + c * 64 + ks2 * 32 + quad * 4);
            float4 bHi = *(const float4*)(b1 + c * 64 + ks2 * 32 + 16 + quad * 4);
            bf16x8 pt[2];
            #pragma unroll
            for (int mt = 0; mt < 2; ++mt) {
                union { bf16x8 v; unsigned short u[8]; } P;
                P.u[0] = f2bf(fmaxf(a1[mt][0][0] + bLo.x, 0.f));
                P.u[1] = f2bf(fmaxf(a1[mt][0][1] + bLo.y, 0.f));
                P.u[2] = f2bf(fmaxf(a1[mt][0][2] + bLo.z, 0.f));
                P.u[3] = f2bf(fmaxf(a1[mt][0][3] + bLo.w, 0.f));
                P.u[4] = f2bf(fmaxf(a1[mt][1][0] + bHi.x, 0.f));
                P.u[5] = f2bf(fmaxf(a1[mt][1][1] + bHi.y, 0.f));
                P.u[6] = f2bf(fmaxf(a1[mt][1][2] + bHi.z, 0.f));
                P.u[7] = f2bf(fmaxf(a1[mt][1][3] + bHi.w, 0.f));
                pt[mt] = P.v;
            }
            // ---- ff2: acc2 += t_chunk @ W2_chunk
            #pragma unroll
            for (int nt = 0; nt < 8; ++nt) {
                const int row = nt * 16 + ln;
                bf16x8 bfr = *(const bf16x8*)
                    &sw2[b][row][(((ks2 * 4 + quad) ^ (row & 7)) * 8)];
                acc2[0][nt] = __builtin_amdgcn_mfma_f32_16x16x32_bf16(pt[0], bfr, acc2[0][nt], 0, 0, 0);
                acc2[1][nt] = __builtin_amdgcn_mfma_f32_16x16x32_bf16(pt[1], bfr, acc2[1][nt], 0, 0, 0);
            }
        }

        asm volatile("s_waitcnt vmcnt(0)" ::: "memory");
        __syncthreads();
    }

    // ---- epilogue: + b2 + residual(h1) -> LN2 -> out
    float gv[8], bv[8], bb[8];
    #pragma unroll
    for (int nt = 0; nt < 8; ++nt) {
        int col = nt * 16 + ln;
        gv[nt] = g2[col]; bv[nt] = bln2[col]; bb[nt] = b2[col];
    }
    #pragma unroll
    for (int mt = 0; mt < 2; ++mt) {
        #pragma unroll
        for (int r = 0; r < 4; ++r) {
            int node = base + w * 32 + mt * 16 + quad * 4 + r;
            bool ok = node < nn;
            float v[8];
            #pragma unroll
            for (int nt = 0; nt < 8; ++nt) {
                int col = nt * 16 + ln;
                float res = ok ? bf2f(h1b[(size_t)node * 128 + col]) : 0.f;
                v[nt] = acc2[mt][nt][r] + bb[nt] + res;
            }
            float s = 0.f;
            #pragma unroll
            for (int nt = 0; nt < 8; ++nt) s += v[nt];
            #pragma unroll
            for (int off = 1; off < 16; off <<= 1) s += __shfl_xor(s, off, 16);
            float mu = s * (1.f / 128.f);
            float q = 0.f;
            #pragma unroll
            for (int nt = 0; nt < 8; ++nt) { float dd = v[nt] - mu; q += dd * dd; }
            #pragma unroll
            for (int off = 1; off < 16; off <<= 1) q += __shfl_xor(q, off, 16);
            float inv = rsqrtf(q * (1.f / 128.f) + LN_EPS);
            if (ok)
                #pragma unroll
                for (int nt = 0; nt < 8; ++nt) {
                    int col = nt * 16 + ln;
                    out[(size_t)node * 128 + col] = (v[nt] - mu) * inv * gv[nt] + bv[nt];
                }
        }
    }
}

// ---------------------------------------------------------------------------
extern "C" void kernel_launch(void* const* d_in, const int* in_sizes, int n_in,
                              void* d_out, int out_size, void* d_ws, size_t ws_size,
                              hipStream_t stream) {
    const float* x    = (const float*)d_in[0];
    const int*   ei   = (const int*)d_in[1];
    const float* Wg   = (const float*)d_in[2];
    const float* atts = (const float*)d_in[3];
    const float* attd = (const float*)d_in[4];
    const float* bgat = (const float*)d_in[5];
    const float* W1   = (const float*)d_in[6];
    const float* b1   = (const float*)d_in[7];
    const float* W2   = (const float*)d_in[8];
    const float* b2   = (const float*)d_in[9];
    const float* g1   = (const float*)d_in[10];
    const float* bln1 = (const float*)d_in[11];
    const float* g2   = (const float*)d_in[12];
    const float* bln2 = (const float*)d_in[13];
    float* out = (float*)d_out;

    const int nn = in_sizes[0] / 128;
    const int E  = in_sizes[1] / 2;
    const int nblk = (nn + 1023) / 1024;

    // workspace: W1s | W2s | Wgt | h1b | hb | a_s | a_d | deg | ptr | bsum | esrc
    uintptr_t pa = ((uintptr_t)d_ws + 15) & ~(uintptr_t)15;
    unsigned short* W1s = (unsigned short*)pa;
    unsigned short* W2s = W1s + 512 * 128;
    unsigned short* Wgt = W2s + 128 * 512;
    unsigned short* h1b = Wgt + 128 * 128;
    unsigned short* hb  = h1b + (size_t)nn * 128;
    float* a_s = (float*)(hb + (size_t)nn * 128);
    float* a_d = a_s + (size_t)nn * 8;
    int*   deg = (int*)(a_d + (size_t)nn * 8);
    int*   ptr = deg + nn;
    int*   bsum = ptr + nn;
    int*   esrc = bsum + 1024;

    hipMemsetAsync(deg, 0, (size_t)nn * sizeof(int), stream);

    k_cvt<<<dim3(256), dim3(256), 0, stream>>>(W1, W2, Wg, W1s, W2s, Wgt);
    k_gat_projm<<<dim3((nn + 63) / 64), dim3(256), 0, stream>>>(
        x, Wgt, atts, attd, hb, a_s, a_d, nn);
    k_deg<<<dim3((E + 255) / 256), dim3(256), 0, stream>>>(ei, deg, E);
    k_scan_blk<<<dim3(nblk), dim3(256), 0, stream>>>(deg, bsum, nn);
    k_scan_top<<<dim3(1), dim3(1024), 0, stream>>>(bsum, nblk);
    k_scan_out<<<dim3(nblk), dim3(256), 0, stream>>>(deg, bsum, ptr, nn);
    k_scatter<<<dim3((E + 255) / 256), dim3(256), 0, stream>>>(ei, ptr, esrc, E);
    k_gather<<<dim3((nn * 16 + 255) / 256), dim3(256), 0, stream>>>(
        esrc, ptr, hb, a_s, a_d, x, bgat, g1, bln1, h1b, nn);

    k_ffu<<<dim3((nn + 127) / 128), dim3(256), 0, stream>>>(
        h1b, W1s, W2s, b1, b2, g2, bln2, out, nn);
}

// Round 7
// 351.855 us; speedup vs baseline: 1.3060x; 1.0104x over previous
//
#include <hip/hip_runtime.h>
#include <hip/hip_bf16.h>
#include <cstddef>
#include <cstdint>

#define NEG_SLOPE 0.2f
#define LN_EPS 1e-5f

typedef __attribute__((ext_vector_type(8))) short bf16x8;
typedef __attribute__((ext_vector_type(8))) unsigned short u16x8;
typedef __attribute__((ext_vector_type(4))) float f32x4;

__device__ __forceinline__ unsigned short f2bf(float f) {
    __hip_bfloat16 h = __float2bfloat16(f);
    return *reinterpret_cast<unsigned short*>(&h);
}
__device__ __forceinline__ float bf2f(unsigned short u) {
    return __uint_as_float(((unsigned)u) << 16);
}
__device__ __forceinline__ float lrelu_exp(float e) {
    e = (e >= 0.f) ? e : NEG_SLOPE * e;
    return expf(e);
}
// async global->LDS, 16B per lane; LDS dest is wave-uniform base + lane*16
__device__ __forceinline__ void gl16(const void* g, void* l) {
    __builtin_amdgcn_global_load_lds(
        (const __attribute__((address_space(1))) unsigned int*)g,
        (__attribute__((address_space(3))) unsigned int*)l, 16, 0, 0);
}

// ---------------------------------------------------------------------------
// GAT projection via bf16 MFMA: h = x @ W_gat, stored bf16 (hb), plus per-head
// logits a_s/a_d (fp32, reduced from the fp32 accumulator before rounding).
// ---------------------------------------------------------------------------
__global__ __launch_bounds__(256, 3) void k_gat_projm(
    const float* __restrict__ x, const unsigned short* __restrict__ Wgt,
    const float* __restrict__ atts, const float* __restrict__ attd,
    unsigned short* __restrict__ hb, float* __restrict__ a_s,
    float* __restrict__ a_d, int nn)
{
    __shared__ __align__(16) unsigned short sx[64][136];   // 17.4 KB
    __shared__ __align__(16) unsigned short sw[128][136];  // 34.8 KB

    const int tid  = threadIdx.x;
    const int base = blockIdx.x * 64;
    const int lane = tid & 63;
    const int w    = tid >> 6;
    const int ln   = lane & 15;
    const int quad = lane >> 4;

    for (int i = tid; i < 2048; i += 256) {
        int row = i >> 4, c = i & 15;
        *(bf16x8*)&sw[row][c * 8] = *(const bf16x8*)(Wgt + row * 128 + c * 8);
    }
    for (int i = tid; i < 2048; i += 256) {
        int row = i >> 5, c = i & 31;
        float4 v = make_float4(0.f, 0.f, 0.f, 0.f);
        if (base + row < nn) v = ((const float4*)(x + (size_t)(base + row) * 128))[c];
        ushort4 o;
        o.x = f2bf(v.x); o.y = f2bf(v.y); o.z = f2bf(v.z); o.w = f2bf(v.w);
        *(ushort4*)&sx[row][c * 4] = o;
    }
    __syncthreads();

    bf16x8 a[4];
    #pragma unroll
    for (int ks = 0; ks < 4; ++ks)
        a[ks] = *(const bf16x8*)&sx[w * 16 + ln][ks * 32 + quad * 8];

    f32x4 acc[8];
    #pragma unroll
    for (int nt = 0; nt < 8; ++nt) acc[nt] = (f32x4){0.f, 0.f, 0.f, 0.f};

    #pragma unroll
    for (int nt = 0; nt < 8; ++nt)
        #pragma unroll
        for (int ks = 0; ks < 4; ++ks) {
            bf16x8 b = *(const bf16x8*)&sw[nt * 16 + ln][ks * 32 + quad * 8];
            acc[nt] = __builtin_amdgcn_mfma_f32_16x16x32_bf16(a[ks], b, acc[nt], 0, 0, 0);
        }

    #pragma unroll
    for (int nt = 0; nt < 8; ++nt) {
        float av = atts[nt * 16 + ln];
        float dv = attd[nt * 16 + ln];
        #pragma unroll
        for (int r = 0; r < 4; ++r) {
            int node = base + w * 16 + quad * 4 + r;
            float val = acc[nt][r];
            float ps = val * av, pd = val * dv;
            #pragma unroll
            for (int off = 1; off < 16; off <<= 1) {
                ps += __shfl_xor(ps, off, 16);
                pd += __shfl_xor(pd, off, 16);
            }
            if (node < nn) {
                hb[(size_t)node * 128 + nt * 16 + ln] = f2bf(val);
                if (ln == 0) {
                    a_s[(size_t)node * 8 + nt] = ps;
                    a_d[(size_t)node * 8 + nt] = pd;
                }
            }
        }
    }
}

// ---------------------------------------------------------------------------
// CSR binning: deg histogram -> two-level exclusive scan -> scatter.
// ---------------------------------------------------------------------------
__global__ __launch_bounds__(256) void k_deg(
    const int* __restrict__ ei, int* __restrict__ deg, int E)
{
    int e = blockIdx.x * 256 + threadIdx.x;
    if (e < E) atomicAdd(&deg[ei[(size_t)E + e]], 1);
}

__global__ __launch_bounds__(256) void k_scan_blk(
    const int* __restrict__ deg, int* __restrict__ bsum, int nn)
{
    __shared__ int ws[4];
    const int tid = threadIdx.x;
    const int base = blockIdx.x * 1024 + tid * 4;
    int4 v = make_int4(0, 0, 0, 0);
    if (base + 3 < nn) v = *(const int4*)(deg + base);
    else {
        if (base + 0 < nn) v.x = deg[base + 0];
        if (base + 1 < nn) v.y = deg[base + 1];
        if (base + 2 < nn) v.z = deg[base + 2];
    }
    int total = v.x + v.y + v.z + v.w;
    #pragma unroll
    for (int off = 32; off; off >>= 1) total += __shfl_xor(total, off, 64);
    if ((tid & 63) == 0) ws[tid >> 6] = total;
    __syncthreads();
    if (tid == 0) bsum[blockIdx.x] = ws[0] + ws[1] + ws[2] + ws[3];
}

__global__ __launch_bounds__(1024) void k_scan_top(int* __restrict__ bsum, int nblk)
{
    __shared__ int part[1024];
    const int tid = threadIdx.x;
    int v = (tid < nblk) ? bsum[tid] : 0;
    part[tid] = v;
    __syncthreads();
    for (int d = 1; d < 1024; d <<= 1) {
        int add = (tid >= d) ? part[tid - d] : 0;
        __syncthreads();
        part[tid] += add;
        __syncthreads();
    }
    if (tid < nblk) bsum[tid] = part[tid] - v;  // exclusive
}

__global__ __launch_bounds__(256) void k_scan_out(
    const int* __restrict__ deg, const int* __restrict__ bsum,
    int* __restrict__ ptr, int nn)
{
    __shared__ int ws[4];
    const int tid = threadIdx.x;
    const int lane = tid & 63;
    const int wid = tid >> 6;
    const int base = blockIdx.x * 1024 + tid * 4;
    int4 v = make_int4(0, 0, 0, 0);
    if (base + 3 < nn) v = *(const int4*)(deg + base);
    else {
        if (base + 0 < nn) v.x = deg[base + 0];
        if (base + 1 < nn) v.y = deg[base + 1];
        if (base + 2 < nn) v.z = deg[base + 2];
    }
    int t1 = v.x + v.y, t2 = t1 + v.z;
    int total = t2 + v.w;
    int inc = total;
    #pragma unroll
    for (int off = 1; off < 64; off <<= 1) {
        int y = __shfl_up(inc, off, 64);
        if (lane >= off) inc += y;
    }
    int wexcl = inc - total;
    if (lane == 63) ws[wid] = inc;
    __syncthreads();
    int woff = 0;
    #pragma unroll
    for (int i = 0; i < 4; ++i) if (i < wid) woff += ws[i];
    int e0 = bsum[blockIdx.x] + woff + wexcl;
    int4 o;
    o.x = e0; o.y = e0 + v.x; o.z = e0 + t1; o.w = e0 + t2;
    if (base + 3 < nn) *(int4*)(ptr + base) = o;
    else {
        if (base + 0 < nn) ptr[base + 0] = o.x;
        if (base + 1 < nn) ptr[base + 1] = o.y;
        if (base + 2 < nn) ptr[base + 2] = o.z;
    }
}

__global__ __launch_bounds__(256) void k_scatter(
    const int* __restrict__ ei, int* __restrict__ ptr,
    int* __restrict__ esrc, int E)
{
    int e = blockIdx.x * 256 + threadIdx.x;
    if (e < E) {
        int pos = atomicAdd(&ptr[ei[(size_t)E + e]], 1);
        esrc[pos] = ei[e];
    }
}

// ---------------------------------------------------------------------------
// Gather + softmax + self-loop + residual + LN1 fused. 16 lanes per dst.
// ---------------------------------------------------------------------------
__global__ __launch_bounds__(256) void k_gather(
    const int* __restrict__ esrc, const int* __restrict__ ptr,
    const unsigned short* __restrict__ hb, const float* __restrict__ a_s,
    const float* __restrict__ a_d, const float* __restrict__ x,
    const float* __restrict__ bgat, const float* __restrict__ g1,
    const float* __restrict__ b1, unsigned short* __restrict__ h1b, int nn)
{
    int d = (blockIdx.x * 256 + threadIdx.x) >> 4;
    if (d >= nn) return;
    const int l = threadIdx.x & 15;     // lane-in-group: 8 channels each
    const int head = l >> 1;            // 2 lanes per head

    const int start = (d == 0) ? 0 : ptr[d - 1];
    const int end = ptr[d];
    const float ad = a_d[(size_t)d * 8 + head];

    float acc[8];
    #pragma unroll
    for (int j = 0; j < 8; ++j) acc[j] = 0.f;
    float wsum = 0.f;

    int e = start;
    for (; e + 4 <= end; e += 4) {
        int s0 = esrc[e + 0], s1 = esrc[e + 1], s2 = esrc[e + 2], s3 = esrc[e + 3];
        float as0 = a_s[(size_t)s0 * 8 + head];
        float as1 = a_s[(size_t)s1 * 8 + head];
        float as2 = a_s[(size_t)s2 * 8 + head];
        float as3 = a_s[(size_t)s3 * 8 + head];
        u16x8 h0 = *(const u16x8*)(hb + (size_t)s0 * 128 + 8 * l);
        u16x8 h1 = *(const u16x8*)(hb + (size_t)s1 * 128 + 8 * l);
        u16x8 h2 = *(const u16x8*)(hb + (size_t)s2 * 128 + 8 * l);
        u16x8 h3 = *(const u16x8*)(hb + (size_t)s3 * 128 + 8 * l);
        float w0 = lrelu_exp(as0 + ad);
        float w1 = lrelu_exp(as1 + ad);
        float w2 = lrelu_exp(as2 + ad);
        float w3 = lrelu_exp(as3 + ad);
        #pragma unroll
        for (int j = 0; j < 8; ++j)
            acc[j] += w0 * bf2f(h0[j]) + w1 * bf2f(h1[j])
                    + w2 * bf2f(h2[j]) + w3 * bf2f(h3[j]);
        wsum += (w0 + w1) + (w2 + w3);
    }
    for (; e < end; ++e) {
        int s = esrc[e];
        float w = lrelu_exp(a_s[(size_t)s * 8 + head] + ad);
        u16x8 hv = *(const u16x8*)(hb + (size_t)s * 128 + 8 * l);
        #pragma unroll
        for (int j = 0; j < 8; ++j) acc[j] += w * bf2f(hv[j]);
        wsum += w;
    }
    {   // self loop
        float w = lrelu_exp(a_s[(size_t)d * 8 + head] + ad);
        u16x8 hv = *(const u16x8*)(hb + (size_t)d * 128 + 8 * l);
        #pragma unroll
        for (int j = 0; j < 8; ++j) acc[j] += w * bf2f(hv[j]);
        wsum += w;
    }
    const float inv_dn = 1.f / wsum;

    float4 xa = *(const float4*)(x + (size_t)d * 128 + 8 * l);
    float4 xb = *(const float4*)(x + (size_t)d * 128 + 8 * l + 4);
    float4 ga = *(const float4*)(bgat + 8 * l);
    float4 gb = *(const float4*)(bgat + 8 * l + 4);
    float v[8];
    v[0] = xa.x + acc[0] * inv_dn + ga.x;
    v[1] = xa.y + acc[1] * inv_dn + ga.y;
    v[2] = xa.z + acc[2] * inv_dn + ga.z;
    v[3] = xa.w + acc[3] * inv_dn + ga.w;
    v[4] = xb.x + acc[4] * inv_dn + gb.x;
    v[5] = xb.y + acc[5] * inv_dn + gb.y;
    v[6] = xb.z + acc[6] * inv_dn + gb.z;
    v[7] = xb.w + acc[7] * inv_dn + gb.w;

    float s = 0.f;
    #pragma unroll
    for (int j = 0; j < 8; ++j) s += v[j];
    #pragma unroll
    for (int off = 1; off < 16; off <<= 1) s += __shfl_xor(s, off, 16);
    float mu = s * (1.f / 128.f);
    float q = 0.f;
    #pragma unroll
    for (int j = 0; j < 8; ++j) { float dd = v[j] - mu; q += dd * dd; }
    #pragma unroll
    for (int off = 1; off < 16; off <<= 1) q += __shfl_xor(q, off, 16);
    float inv = rsqrtf(q * (1.f / 128.f) + LN_EPS);

    float4 g1a = *(const float4*)(g1 + 8 * l);
    float4 g1b = *(const float4*)(g1 + 8 * l + 4);
    float4 b1a = *(const float4*)(b1 + 8 * l);
    float4 b1b = *(const float4*)(b1 + 8 * l + 4);
    union { u16x8 v8; unsigned short u[8]; } ob;
    ob.u[0] = f2bf((v[0] - mu) * inv * g1a.x + b1a.x);
    ob.u[1] = f2bf((v[1] - mu) * inv * g1a.y + b1a.y);
    ob.u[2] = f2bf((v[2] - mu) * inv * g1a.z + b1a.z);
    ob.u[3] = f2bf((v[3] - mu) * inv * g1a.w + b1a.w);
    ob.u[4] = f2bf((v[4] - mu) * inv * g1b.x + b1b.x);
    ob.u[5] = f2bf((v[5] - mu) * inv * g1b.y + b1b.y);
    ob.u[6] = f2bf((v[6] - mu) * inv * g1b.z + b1b.z);
    ob.u[7] = f2bf((v[7] - mu) * inv * g1b.w + b1b.w);
    *(u16x8*)(h1b + (size_t)d * 128 + 8 * l) = ob.v8;
}

// ---------------------------------------------------------------------------
// Weight convert for k_ffu's chunk-32 global_load_lds pipeline. LDS images
// linear; swizzles baked into the GLOBAL layouts (both-sides-or-neither):
//   W1s: [512 ffrow][128 k]  W1s[n][8g+j] = W1[8*(g^(n&7)) + j][n]
//        (XOR over 16 granules/row with row&7 -> 2-way free on ds_read)
//   W2s: [16 c32][128 outrow][32], element (c32,row,8g+j) holds W2[ff][row],
//        gr = g^(row&3), ff = c32*32 + perm(gr,j),
//        perm(q,j) = j<4 ? 4q+j : 16+4q+(j-4)  (ff2 A-frag register k-order)
// ---------------------------------------------------------------------------
__global__ __launch_bounds__(256) void k_cvt(
    const float* __restrict__ W1, const float* __restrict__ W2,
    const float* __restrict__ Wg,
    unsigned short* __restrict__ W1s, unsigned short* __restrict__ W2s,
    unsigned short* __restrict__ Wgt)
{
    int t = blockIdx.x * 256 + threadIdx.x;
    if (t < 512 * 128) {
        // W1s
        int n = t >> 7, col = t & 127;
        int g = col >> 3, j = col & 7;
        int sk = 8 * (g ^ (n & 7)) + j;
        W1s[t] = f2bf(W1[(size_t)sk * 512 + n]);
        // W2s: t = c32*4096 + row*32 + g2*8 + j2
        int j2 = t & 7, g2 = (t >> 3) & 3, row = (t >> 5) & 127, c32 = t >> 12;
        int gr = g2 ^ (row & 3);
        int ff = c32 * 32 + (j2 < 4 ? 4 * gr + j2 : 16 + 4 * gr + (j2 - 4));
        W2s[t] = f2bf(W2[(size_t)ff * 128 + row]);
        if (t < 128 * 128) {
            int n3 = t >> 7, k3 = t & 127;
            Wgt[t] = f2bf(Wg[(size_t)k3 * 128 + n3]);
        }
    }
}

// ---------------------------------------------------------------------------
// Fully fused FF: out = LN2( relu(h1 @ W1 + b1) @ W2 + b2 + h1 ).
// 4-buffer chunk-32 counted-vmcnt pipeline (T3+T4+T5):
//   prologue: stage chunks 0,1,2 (12 gl16/wave outstanding)
//   loop c (fully unrolled, 16 chunks):
//     vmcnt(8)  <- oldest batch (c) landed; batches c+1,c+2 stay IN FLIGHT
//     raw s_barrier (NOT __syncthreads -- that drains vmcnt(0), the R3 stall)
//     issue stage(c+3) into buf (c+3)&3   (safe: buf last read in chunk c-1,
//                                          all waves passed this barrier)
//     setprio(1) ff1 MFMAs setprio(0); pack; setprio(1) ff2 MFMAs setprio(0)
//   tail: vmcnt(4) at c=14, vmcnt(0) at c=15.
// LDS 64 KB (4 x (8KB W1 + 8KB W2)) -> 2 blocks/CU; 256 thr, 128 nodes/block,
// grid 782 (R4 showed grid-391 starves CUs). Loads now have ~3 chunk-times to
// land instead of one compute phase, and barriers no longer drain the queue.
// ---------------------------------------------------------------------------
__global__ __launch_bounds__(256, 2) void k_ffu(
    const unsigned short* __restrict__ h1b,
    const unsigned short* __restrict__ W1s,   // [512][128] swizzled
    const unsigned short* __restrict__ W2s,   // [16][128][32] permuted+swizzled
    const float* __restrict__ b1, const float* __restrict__ b2,
    const float* __restrict__ g2, const float* __restrict__ bln2,
    float* __restrict__ out, int nn)
{
    __shared__ __align__(16) unsigned short sw1[4][32][128];  // 4 x 8 KB
    __shared__ __align__(16) unsigned short sw2[4][128][32];  // 4 x 8 KB

    const int tid  = threadIdx.x;        // 0..255
    const int base = blockIdx.x * 128;
    const int lane = tid & 63;
    const int w    = tid >> 6;           // 0..3
    const int ln   = lane & 15;
    const int quad = lane >> 4;
    const int wun  = tid & ~63;          // w*64 (wave-uniform)

    // persistent h1 fragments (B-operand of swapped ff1)
    const bf16x8 zf = {0, 0, 0, 0, 0, 0, 0, 0};
    bf16x8 hfrag[2][4];
    #pragma unroll
    for (int mt = 0; mt < 2; ++mt) {
        int node = base + w * 32 + mt * 16 + ln;
        #pragma unroll
        for (int ks = 0; ks < 4; ++ks)
            hfrag[mt][ks] = (node < nn)
                ? *(const bf16x8*)(h1b + (size_t)node * 128 + ks * 32 + quad * 8)
                : zf;
    }

    f32x4 acc2[2][8];
    #pragma unroll
    for (int mt = 0; mt < 2; ++mt)
        #pragma unroll
        for (int nt = 0; nt < 8; ++nt)
            acc2[mt][nt] = (f32x4){0.f, 0.f, 0.f, 0.f};

    // stage batch cc (4 gl16/thread: 2 W1 + 2 W2) into buffer bb
    #define STAGE(cc, bb) do {                                                  \
        const unsigned short* gp1 = W1s + (size_t)(cc) * 4096;                  \
        const unsigned short* gp2 = W2s + (size_t)(cc) * 4096;                  \
        gl16(gp1 + (size_t)tid * 8,         &sw1[bb][0][0] + (size_t)wun * 8);  \
        gl16(gp1 + (size_t)(256 + tid) * 8, &sw1[bb][0][0] + (size_t)(256 + wun) * 8); \
        gl16(gp2 + (size_t)tid * 8,         &sw2[bb][0][0] + (size_t)wun * 8);  \
        gl16(gp2 + (size_t)(256 + tid) * 8, &sw2[bb][0][0] + (size_t)(256 + wun) * 8); \
    } while (0)

    STAGE(0, 0);
    STAGE(1, 1);
    STAGE(2, 2);

    #pragma unroll
    for (int c = 0; c < 16; ++c) {
        // wait for batch c only; keep later batches in flight
        if (c <= 13)      asm volatile("s_waitcnt vmcnt(8)" ::: "memory");
        else if (c == 14) asm volatile("s_waitcnt vmcnt(4)" ::: "memory");
        else              asm volatile("s_waitcnt vmcnt(0)" ::: "memory");
        __builtin_amdgcn_s_barrier();
        if (c + 3 < 16) STAGE(c + 3, (c + 3) & 3);
        const int bb = c & 3;

        // ---- ff1 (swapped): t^T for ff block [c*32, c*32+32)
        f32x4 a1[2][2];
        a1[0][0] = (f32x4){0.f, 0.f, 0.f, 0.f};
        a1[0][1] = (f32x4){0.f, 0.f, 0.f, 0.f};
        a1[1][0] = (f32x4){0.f, 0.f, 0.f, 0.f};
        a1[1][1] = (f32x4){0.f, 0.f, 0.f, 0.f};
        __builtin_amdgcn_s_setprio(1);
        #pragma unroll
        for (int fh = 0; fh < 2; ++fh) {
            const int row = fh * 16 + ln;
            #pragma unroll
            for (int ks = 0; ks < 4; ++ks) {
                bf16x8 a = *(const bf16x8*)
                    &sw1[bb][row][(((ks * 4 + quad) ^ (row & 7)) * 8)];
                a1[0][fh] = __builtin_amdgcn_mfma_f32_16x16x32_bf16(a, hfrag[0][ks], a1[0][fh], 0, 0, 0);
                a1[1][fh] = __builtin_amdgcn_mfma_f32_16x16x32_bf16(a, hfrag[1][ks], a1[1][fh], 0, 0, 0);
            }
        }
        __builtin_amdgcn_s_setprio(0);

        // ---- bias + relu + pack to ff2 A-frag (permuted k-order, in-lane)
        float4 bLo = *(const float4*)(b1 + c * 32 + quad * 4);
        float4 bHi = *(const float4*)(b1 + c * 32 + 16 + quad * 4);
        bf16x8 pt[2];
        #pragma unroll
        for (int mt = 0; mt < 2; ++mt) {
            union { bf16x8 v; unsigned short u[8]; } P;
            P.u[0] = f2bf(fmaxf(a1[mt][0][0] + bLo.x, 0.f));
            P.u[1] = f2bf(fmaxf(a1[mt][0][1] + bLo.y, 0.f));
            P.u[2] = f2bf(fmaxf(a1[mt][0][2] + bLo.z, 0.f));
            P.u[3] = f2bf(fmaxf(a1[mt][0][3] + bLo.w, 0.f));
            P.u[4] = f2bf(fmaxf(a1[mt][1][0] + bHi.x, 0.f));
            P.u[5] = f2bf(fmaxf(a1[mt][1][1] + bHi.y, 0.f));
            P.u[6] = f2bf(fmaxf(a1[mt][1][2] + bHi.z, 0.f));
            P.u[7] = f2bf(fmaxf(a1[mt][1][3] + bHi.w, 0.f));
            pt[mt] = P.v;
        }

        // ---- ff2: acc2 += t_chunk @ W2_chunk
        __builtin_amdgcn_s_setprio(1);
        #pragma unroll
        for (int nt = 0; nt < 8; ++nt) {
            const int row = nt * 16 + ln;
            bf16x8 bfr = *(const bf16x8*)
                &sw2[bb][row][((quad ^ (row & 3)) * 8)];
            acc2[0][nt] = __builtin_amdgcn_mfma_f32_16x16x32_bf16(pt[0], bfr, acc2[0][nt], 0, 0, 0);
            acc2[1][nt] = __builtin_amdgcn_mfma_f32_16x16x32_bf16(pt[1], bfr, acc2[1][nt], 0, 0, 0);
        }
        __builtin_amdgcn_s_setprio(0);
    }
    #undef STAGE

    // ---- epilogue: + b2 + residual(h1) -> LN2 -> out
    float gv[8], bv[8], bb[8];
    #pragma unroll
    for (int nt = 0; nt < 8; ++nt) {
        int col = nt * 16 + ln;
        gv[nt] = g2[col]; bv[nt] = bln2[col]; bb[nt] = b2[col];
    }
    #pragma unroll
    for (int mt = 0; mt < 2; ++mt) {
        #pragma unroll
        for (int r = 0; r < 4; ++r) {
            int node = base + w * 32 + mt * 16 + quad * 4 + r;
            bool ok = node < nn;
            float v[8];
            #pragma unroll
            for (int nt = 0; nt < 8; ++nt) {
                int col = nt * 16 + ln;
                float res = ok ? bf2f(h1b[(size_t)node * 128 + col]) : 0.f;
                v[nt] = acc2[mt][nt][r] + bb[nt] + res;
            }
            float s = 0.f;
            #pragma unroll
            for (int nt = 0; nt < 8; ++nt) s += v[nt];
            #pragma unroll
            for (int off = 1; off < 16; off <<= 1) s += __shfl_xor(s, off, 16);
            float mu = s * (1.f / 128.f);
            float q = 0.f;
            #pragma unroll
            for (int nt = 0; nt < 8; ++nt) { float dd = v[nt] - mu; q += dd * dd; }
            #pragma unroll
            for (int off = 1; off < 16; off <<= 1) q += __shfl_xor(q, off, 16);
            float inv = rsqrtf(q * (1.f / 128.f) + LN_EPS);
            if (ok)
                #pragma unroll
                for (int nt = 0; nt < 8; ++nt) {
                    int col = nt * 16 + ln;
                    out[(size_t)node * 128 + col] = (v[nt] - mu) * inv * gv[nt] + bv[nt];
                }
        }
    }
}

// ---------------------------------------------------------------------------
extern "C" void kernel_launch(void* const* d_in, const int* in_sizes, int n_in,
                              void* d_out, int out_size, void* d_ws, size_t ws_size,
                              hipStream_t stream) {
    const float* x    = (const float*)d_in[0];
    const int*   ei   = (const int*)d_in[1];
    const float* Wg   = (const float*)d_in[2];
    const float* atts = (const float*)d_in[3];
    const float* attd = (const float*)d_in[4];
    const float* bgat = (const float*)d_in[5];
    const float* W1   = (const float*)d_in[6];
    const float* b1   = (const float*)d_in[7];
    const float* W2   = (const float*)d_in[8];
    const float* b2   = (const float*)d_in[9];
    const float* g1   = (const float*)d_in[10];
    const float* bln1 = (const float*)d_in[11];
    const float* g2   = (const float*)d_in[12];
    const float* bln2 = (const float*)d_in[13];
    float* out = (float*)d_out;

    const int nn = in_sizes[0] / 128;
    const int E  = in_sizes[1] / 2;
    const int nblk = (nn + 1023) / 1024;

    // workspace: W1s | W2s | Wgt | h1b | hb | a_s | a_d | deg | ptr | bsum | esrc
    uintptr_t pa = ((uintptr_t)d_ws + 15) & ~(uintptr_t)15;
    unsigned short* W1s = (unsigned short*)pa;
    unsigned short* W2s = W1s + 512 * 128;
    unsigned short* Wgt = W2s + 128 * 512;
    unsigned short* h1b = Wgt + 128 * 128;
    unsigned short* hb  = h1b + (size_t)nn * 128;
    float* a_s = (float*)(hb + (size_t)nn * 128);
    float* a_d = a_s + (size_t)nn * 8;
    int*   deg = (int*)(a_d + (size_t)nn * 8);
    int*   ptr = deg + nn;
    int*   bsum = ptr + nn;
    int*   esrc = bsum + 1024;

    hipMemsetAsync(deg, 0, (size_t)nn * sizeof(int), stream);

    k_cvt<<<dim3(256), dim3(256), 0, stream>>>(W1, W2, Wg, W1s, W2s, Wgt);
    k_gat_projm<<<dim3((nn + 63) / 64), dim3(256), 0, stream>>>(
        x, Wgt, atts, attd, hb, a_s, a_d, nn);
    k_deg<<<dim3((E + 255) / 256), dim3(256), 0, stream>>>(ei, deg, E);
    k_scan_blk<<<dim3(nblk), dim3(256), 0, stream>>>(deg, bsum, nn);
    k_scan_top<<<dim3(1), dim3(1024), 0, stream>>>(bsum, nblk);
    k_scan_out<<<dim3(nblk), dim3(256), 0, stream>>>(deg, bsum, ptr, nn);
    k_scatter<<<dim3((E + 255) / 256), dim3(256), 0, stream>>>(ei, ptr, esrc, E);
    k_gather<<<dim3((nn * 16 + 255) / 256), dim3(256), 0, stream>>>(
        esrc, ptr, hb, a_s, a_d, x, bgat, g1, bln1, h1b, nn);

    k_ffu<<<dim3((nn + 127) / 128), dim3(256), 0, stream>>>(
        h1b, W1s, W2s, b1, b2, g2, bln2, out, nn);
}